// Round 7
// baseline (207.165 us; speedup 1.0000x reference)
//
#include <hip/hip_runtime.h>
#include <hip/hip_bf16.h>

constexpr int B = 8;
constexpr int C = 512;
constexpr int M = 64;
constexpr int N = 4096;
constexpr float EPS = 1e-6f;
constexpr int NTS = 16;   // n-split for s_kernel -> (8,16,8)=1024 blocks, 4 iters each
constexpr int LDP = 72;   // bf16 LDS row pitch
constexpr int LDPF = 68;  // f32 bounce row pitch

typedef __attribute__((ext_vector_type(8))) short short8v;
typedef __attribute__((ext_vector_type(4))) short short4v;
typedef __attribute__((ext_vector_type(4))) float f32x4;

__device__ __forceinline__ short f2b(float f) {
  union { __hip_bfloat16 h; short s; } u;
  u.h = __float2bfloat16(f);
  return u.s;
}
__device__ __forceinline__ float b2f(short s) {
  union { __hip_bfloat16 h; short s2; } u;
  u.s2 = s;
  return __bfloat162float(u.h);
}

// ---------------------------------------------------------------------------
// prep: weights f32 -> bf16, zero Ksum & xsum.
// ---------------------------------------------------------------------------
__global__ __launch_bounds__(256) void prep_kernel(
    const float* __restrict__ Wq, const float* __restrict__ Wk,
    const float* __restrict__ Wv, short* __restrict__ Wq_bf,
    short* __restrict__ Wk_bf, short* __restrict__ Wv_bf,
    float* __restrict__ Ksum, float* __restrict__ xsum) {
  const int id = blockIdx.x * 256 + threadIdx.x;
  const int stride = gridDim.x * 256;
  for (int i = id; i < C * M / 4; i += stride) {
    const float4 a = reinterpret_cast<const float4*>(Wq)[i];
    const float4 b = reinterpret_cast<const float4*>(Wk)[i];
    short4v sa = {f2b(a.x), f2b(a.y), f2b(a.z), f2b(a.w)};
    short4v sb = {f2b(b.x), f2b(b.y), f2b(b.z), f2b(b.w)};
    reinterpret_cast<short4v*>(Wq_bf)[i] = sa;
    reinterpret_cast<short4v*>(Wk_bf)[i] = sb;
  }
  for (int i = id; i < C * C / 4; i += stride) {
    const float4 a = reinterpret_cast<const float4*>(Wv)[i];
    short4v sa = {f2b(a.x), f2b(a.y), f2b(a.z), f2b(a.w)};
    reinterpret_cast<short4v*>(Wv_bf)[i] = sa;
  }
  for (int i = id; i < B * M + B * C; i += stride) {
    if (i < B * M) Ksum[i] = 0.f;
    else xsum[i - B * M] = 0.f;
  }
}

// ---------------------------------------------------------------------------
// qk: D[m][n] = Wq/Wk[m][cK] x xT[n][cK] via MFMA; L2-normalize per n;
// writes QnT_bf[b][n][m], Kn_bf[b][m][n]; Ksum via shfl+atomics.
// T14: next c-tile's globals prefetched to regs during MFMA.
// ---------------------------------------------------------------------------
__global__ __launch_bounds__(256) void qk_kernel(
    const float* __restrict__ x, const short* __restrict__ Wq_bf,
    const float* __restrict__ bq, const short* __restrict__ Wk_bf,
    const float* __restrict__ bk, short* __restrict__ QnT,
    short* __restrict__ KnB, float* __restrict__ Ksum) {
  __shared__ short aq[64 * LDP];  // Wq tile [m][cK]
  __shared__ short ak[64 * LDP];  // Wk tile [m][cK]
  __shared__ short bx[64 * LDP];  // xT tile [n][cK]
  __shared__ float colred[2][4][64];
  __shared__ float rsq[2][64];
  const int t = threadIdx.x;
  const int n0 = blockIdx.x * 64;
  const int b = blockIdx.y;
  const int w = t >> 6, l = t & 63, l15 = l & 15, kg = l >> 4;
  const int sr = t >> 2, sko = (t & 3) * 16;  // weight-stage row/col
  const int cr = t & 63, ng = t >> 6;         // x-stage row/col-group
  f32x4 accQ[4], accK[4];
#pragma unroll
  for (int i = 0; i < 4; ++i) { accQ[i] = f32x4{0.f, 0.f, 0.f, 0.f}; accK[i] = f32x4{0.f, 0.f, 0.f, 0.f}; }

  short8v wq0, wq1, wk0, wk1;
  float4 xr[4];
  // prologue: c0 = 0
  {
    wq0 = *reinterpret_cast<const short8v*>(&Wq_bf[sr * C + sko]);
    wq1 = *reinterpret_cast<const short8v*>(&Wq_bf[sr * C + sko + 8]);
    wk0 = *reinterpret_cast<const short8v*>(&Wk_bf[sr * C + sko]);
    wk1 = *reinterpret_cast<const short8v*>(&Wk_bf[sr * C + sko + 8]);
    const float* xg = x + ((size_t)b * C + cr) * N + n0 + ng * 16;
#pragma unroll
    for (int i = 0; i < 4; ++i) xr[i] = *reinterpret_cast<const float4*>(xg + 4 * i);
  }
  for (int c0 = 0; c0 < C; c0 += 64) {
    __syncthreads();
    *reinterpret_cast<short8v*>(&aq[sr * LDP + sko]) = wq0;
    *reinterpret_cast<short8v*>(&aq[sr * LDP + sko + 8]) = wq1;
    *reinterpret_cast<short8v*>(&ak[sr * LDP + sko]) = wk0;
    *reinterpret_cast<short8v*>(&ak[sr * LDP + sko + 8]) = wk1;
#pragma unroll
    for (int i = 0; i < 4; ++i) {  // transposed x writes (2-way banked, free)
      bx[(ng * 16 + 4 * i + 0) * LDP + cr] = f2b(xr[i].x);
      bx[(ng * 16 + 4 * i + 1) * LDP + cr] = f2b(xr[i].y);
      bx[(ng * 16 + 4 * i + 2) * LDP + cr] = f2b(xr[i].z);
      bx[(ng * 16 + 4 * i + 3) * LDP + cr] = f2b(xr[i].w);
    }
    __syncthreads();
    if (c0 + 64 < C) {  // T14: issue next tile loads before MFMA
      const int c1 = c0 + 64;
      wq0 = *reinterpret_cast<const short8v*>(&Wq_bf[sr * C + c1 + sko]);
      wq1 = *reinterpret_cast<const short8v*>(&Wq_bf[sr * C + c1 + sko + 8]);
      wk0 = *reinterpret_cast<const short8v*>(&Wk_bf[sr * C + c1 + sko]);
      wk1 = *reinterpret_cast<const short8v*>(&Wk_bf[sr * C + c1 + sko + 8]);
      const float* xg = x + ((size_t)b * C + c1 + cr) * N + n0 + ng * 16;
#pragma unroll
      for (int i = 0; i < 4; ++i) xr[i] = *reinterpret_cast<const float4*>(xg + 4 * i);
    }
#pragma unroll
    for (int ks = 0; ks < 2; ++ks) {
      const short8v afq = *reinterpret_cast<const short8v*>(&aq[(w * 16 + l15) * LDP + ks * 32 + kg * 8]);
      const short8v afk = *reinterpret_cast<const short8v*>(&ak[(w * 16 + l15) * LDP + ks * 32 + kg * 8]);
#pragma unroll
      for (int tc = 0; tc < 4; ++tc) {
        const short8v bf = *reinterpret_cast<const short8v*>(&bx[(tc * 16 + l15) * LDP + ks * 32 + kg * 8]);
        accQ[tc] = __builtin_amdgcn_mfma_f32_16x16x32_bf16(afq, bf, accQ[tc], 0, 0, 0);
        accK[tc] = __builtin_amdgcn_mfma_f32_16x16x32_bf16(afk, bf, accK[tc], 0, 0, 0);
      }
    }
  }
  // bias (row = w*16 + kg*4 + reg)
  {
    const float4 q4 = *reinterpret_cast<const float4*>(&bq[w * 16 + kg * 4]);
    const float4 k4 = *reinterpret_cast<const float4*>(&bk[w * 16 + kg * 4]);
    const float bqa[4] = {q4.x, q4.y, q4.z, q4.w};
    const float bka[4] = {k4.x, k4.y, k4.z, k4.w};
#pragma unroll
    for (int tc = 0; tc < 4; ++tc)
#pragma unroll
      for (int r = 0; r < 4; ++r) { accQ[tc][r] += bqa[r]; accK[tc][r] += bka[r]; }
  }
  // per-position (n) sum of squares over m
#pragma unroll
  for (int tc = 0; tc < 4; ++tc) {
    float vq = accQ[tc][0] * accQ[tc][0] + accQ[tc][1] * accQ[tc][1] +
               accQ[tc][2] * accQ[tc][2] + accQ[tc][3] * accQ[tc][3];
    float vk = accK[tc][0] * accK[tc][0] + accK[tc][1] * accK[tc][1] +
               accK[tc][2] * accK[tc][2] + accK[tc][3] * accK[tc][3];
    vq += __shfl_xor(vq, 16, 64); vq += __shfl_xor(vq, 32, 64);
    vk += __shfl_xor(vk, 16, 64); vk += __shfl_xor(vk, 32, 64);
    if (l < 16) { colred[0][w][tc * 16 + l] = vq; colred[1][w][tc * 16 + l] = vk; }
  }
  __syncthreads();
  if (t < 128) {
    const int which = t >> 6, n = t & 63;
    const float s = colred[which][0][n] + colred[which][1][n] +
                    colred[which][2][n] + colred[which][3][n];
    rsq[which][n] = 1.0f / sqrtf(s);
  }
  __syncthreads();
  // normalize + Ksum row partials
  float ksr[4] = {0.f, 0.f, 0.f, 0.f};
#pragma unroll
  for (int tc = 0; tc < 4; ++tc) {
    const float rq = rsq[0][tc * 16 + l15], rk = rsq[1][tc * 16 + l15];
#pragma unroll
    for (int r = 0; r < 4; ++r) { accQ[tc][r] *= rq; accK[tc][r] *= rk; ksr[r] += accK[tc][r]; }
  }
#pragma unroll
  for (int r = 0; r < 4; ++r) {
    float s = ksr[r];
    s += __shfl_xor(s, 1, 64); s += __shfl_xor(s, 2, 64);
    s += __shfl_xor(s, 4, 64); s += __shfl_xor(s, 8, 64);
    if (l15 == 0) atomicAdd(&Ksum[b * M + w * 16 + kg * 4 + r], s);
  }
  // bounce: QnT into aq [n][m], Kn into ak [m][n]
#pragma unroll
  for (int tc = 0; tc < 4; ++tc) {
    short4v q4 = {f2b(accQ[tc][0]), f2b(accQ[tc][1]), f2b(accQ[tc][2]), f2b(accQ[tc][3])};
    *reinterpret_cast<short4v*>(&aq[(tc * 16 + l15) * LDP + w * 16 + kg * 4]) = q4;
#pragma unroll
    for (int r = 0; r < 4; ++r)
      ak[(w * 16 + kg * 4 + r) * LDP + tc * 16 + l15] = f2b(accK[tc][r]);
  }
  __syncthreads();
  {
    short* qg = QnT + ((size_t)b * N + n0 + sr) * M + sko;
    *reinterpret_cast<short8v*>(qg) = *reinterpret_cast<const short8v*>(&aq[sr * LDP + sko]);
    *reinterpret_cast<short8v*>(qg + 8) = *reinterpret_cast<const short8v*>(&aq[sr * LDP + sko + 8]);
    short* kg2 = KnB + ((size_t)b * M + sr) * N + n0 + sko;
    *reinterpret_cast<short8v*>(kg2) = *reinterpret_cast<const short8v*>(&ak[sr * LDP + sko]);
    *reinterpret_cast<short8v*>(kg2 + 8) = *reinterpret_cast<const short8v*>(&ak[sr * LDP + sko + 8]);
  }
}

// ---------------------------------------------------------------------------
// s: S'[m][c'] = Kn[m][nK] x x[c'][nK] over this block's n-range; bf16
// partials (no atomics); fuses xsum. T14 reg-prefetch.
// ---------------------------------------------------------------------------
__global__ __launch_bounds__(256) void s_kernel(
    const float* __restrict__ x, const short* __restrict__ KnB,
    short* __restrict__ Spart, float* __restrict__ xsum) {
  __shared__ short sm[2 * 64 * LDP];  // ka | xb ; reused as bf16 bounce
  __shared__ float red[256];
  short* ka = sm;
  short* xb = sm + 64 * LDP;
  const int t = threadIdx.x;
  const int c0 = blockIdx.x * 64;
  const int nt = blockIdx.y;
  const int b = blockIdx.z;
  const int w = t >> 6, l = t & 63, l15 = l & 15, kg = l >> 4;
  const int sr = t >> 2, sko = (t & 3) * 16;
  f32x4 acc[4];
#pragma unroll
  for (int i = 0; i < 4; ++i) acc[i] = f32x4{0.f, 0.f, 0.f, 0.f};
  float xacc = 0.f;
  constexpr int ITERS = N / NTS / 64;  // 4
  const int nbase = nt * (N / NTS);
  short8v k0r, k1r;
  float4 xr[4];
  {  // prologue it=0
    const short* kp = &KnB[((size_t)b * M + sr) * N + nbase + sko];
    k0r = *reinterpret_cast<const short8v*>(kp);
    k1r = *reinterpret_cast<const short8v*>(kp + 8);
    const float* xg = x + ((size_t)b * C + c0 + sr) * N + nbase + sko;
#pragma unroll
    for (int i = 0; i < 4; ++i) xr[i] = *reinterpret_cast<const float4*>(xg + 4 * i);
  }
  for (int it = 0; it < ITERS; ++it) {
    __syncthreads();
    *reinterpret_cast<short8v*>(&ka[sr * LDP + sko]) = k0r;
    *reinterpret_cast<short8v*>(&ka[sr * LDP + sko + 8]) = k1r;
    short tmp[16];
#pragma unroll
    for (int i = 0; i < 4; ++i) {
      tmp[4 * i + 0] = f2b(xr[i].x); tmp[4 * i + 1] = f2b(xr[i].y);
      tmp[4 * i + 2] = f2b(xr[i].z); tmp[4 * i + 3] = f2b(xr[i].w);
      xacc += xr[i].x + xr[i].y + xr[i].z + xr[i].w;
    }
    *reinterpret_cast<short8v*>(&xb[sr * LDP + sko]) = *reinterpret_cast<const short8v*>(&tmp[0]);
    *reinterpret_cast<short8v*>(&xb[sr * LDP + sko + 8]) = *reinterpret_cast<const short8v*>(&tmp[8]);
    __syncthreads();
    if (it + 1 < ITERS) {  // T14
      const int nk = nbase + (it + 1) * 64;
      const short* kp = &KnB[((size_t)b * M + sr) * N + nk + sko];
      k0r = *reinterpret_cast<const short8v*>(kp);
      k1r = *reinterpret_cast<const short8v*>(kp + 8);
      const float* xg = x + ((size_t)b * C + c0 + sr) * N + nk + sko;
#pragma unroll
      for (int i = 0; i < 4; ++i) xr[i] = *reinterpret_cast<const float4*>(xg + 4 * i);
    }
#pragma unroll
    for (int ks = 0; ks < 2; ++ks) {
      const short8v af = *reinterpret_cast<const short8v*>(&ka[(w * 16 + l15) * LDP + ks * 32 + kg * 8]);
#pragma unroll
      for (int tc = 0; tc < 4; ++tc) {
        const short8v bf = *reinterpret_cast<const short8v*>(&xb[(tc * 16 + l15) * LDP + ks * 32 + kg * 8]);
        acc[tc] = __builtin_amdgcn_mfma_f32_16x16x32_bf16(af, bf, acc[tc], 0, 0, 0);
      }
    }
  }
  red[t] = xacc;
  __syncthreads();  // also guarantees all MFMA LDS reads done
  if (t < 64)
    atomicAdd(&xsum[b * C + c0 + t], red[4 * t] + red[4 * t + 1] + red[4 * t + 2] + red[4 * t + 3]);
  // bounce S' bf16 [m][c'] into sm
#pragma unroll
  for (int tc = 0; tc < 4; ++tc)
#pragma unroll
    for (int r = 0; r < 4; ++r)
      sm[(w * 16 + kg * 4 + r) * LDP + tc * 16 + l15] = f2b(acc[tc][r]);
  __syncthreads();
  {
    short* gp = Spart + (((size_t)nt * B + b) * M + sr) * C + c0 + sko;
    *reinterpret_cast<short8v*>(gp) = *reinterpret_cast<const short8v*>(&sm[sr * LDP + sko]);
    *reinterpret_cast<short8v*>(gp + 8) = *reinterpret_cast<const short8v*>(&sm[sr * LDP + sko + 8]);
  }
}

// ---------------------------------------------------------------------------
// matm: matMT[c][m] = Wv[c][c'K] x S'[m][c'K] + bv[c]*Ksum[m]  (bf16 out)
// Staging folds the NTS bf16 partials of S'. Fused vsum GEMV.
// ---------------------------------------------------------------------------
__global__ __launch_bounds__(256) void matm_kernel(
    const short* __restrict__ Wv_bf, const float* __restrict__ bv,
    const short* __restrict__ Spart, const float* __restrict__ xsum,
    const float* __restrict__ Ksum, short* __restrict__ matMT,
    float* __restrict__ vsum) {
  __shared__ short wa[64 * LDP];
  __shared__ short sb[64 * LDP];
  __shared__ float xs[64];
  const int t = threadIdx.x;
  const int c0 = blockIdx.x * 64;
  const int b = blockIdx.y;
  const int w = t >> 6, l = t & 63, l15 = l & 15, kg = l >> 4;
  const int sr = t >> 2, sko = (t & 3) * 16;
  f32x4 acc[4];
#pragma unroll
  for (int i = 0; i < 4; ++i) acc[i] = f32x4{0.f, 0.f, 0.f, 0.f};
  float vacc = 0.f;
  for (int k0 = 0; k0 < C; k0 += 64) {
    __syncthreads();
    *reinterpret_cast<short8v*>(&wa[sr * LDP + sko]) =
        *reinterpret_cast<const short8v*>(&Wv_bf[(size_t)(c0 + sr) * C + k0 + sko]);
    *reinterpret_cast<short8v*>(&wa[sr * LDP + sko + 8]) =
        *reinterpret_cast<const short8v*>(&Wv_bf[(size_t)(c0 + sr) * C + k0 + sko + 8]);
    {  // fold NTS partials of S'[m=sr][k0+sko .. +15]
      float sacc[16];
#pragma unroll
      for (int j = 0; j < 16; ++j) sacc[j] = 0.f;
#pragma unroll 4
      for (int nt2 = 0; nt2 < NTS; ++nt2) {
        const short* sp = Spart + (((size_t)nt2 * B + b) * M + sr) * C + k0 + sko;
        const short8v p0 = *reinterpret_cast<const short8v*>(sp);
        const short8v p1 = *reinterpret_cast<const short8v*>(sp + 8);
#pragma unroll
        for (int j = 0; j < 8; ++j) { sacc[j] += b2f(p0[j]); sacc[8 + j] += b2f(p1[j]); }
      }
      short tmp[16];
#pragma unroll
      for (int j = 0; j < 16; ++j) tmp[j] = f2b(sacc[j]);
      *reinterpret_cast<short8v*>(&sb[sr * LDP + sko]) = *reinterpret_cast<const short8v*>(&tmp[0]);
      *reinterpret_cast<short8v*>(&sb[sr * LDP + sko + 8]) = *reinterpret_cast<const short8v*>(&tmp[8]);
    }
    if (t < 64) xs[t] = xsum[b * C + k0 + t];
    __syncthreads();
#pragma unroll
    for (int ks = 0; ks < 2; ++ks) {
      const short8v af = *reinterpret_cast<const short8v*>(&wa[(w * 16 + l15) * LDP + ks * 32 + kg * 8]);
#pragma unroll
      for (int tc = 0; tc < 4; ++tc) {
        const short8v bf = *reinterpret_cast<const short8v*>(&sb[(tc * 16 + l15) * LDP + ks * 32 + kg * 8]);
        acc[tc] = __builtin_amdgcn_mfma_f32_16x16x32_bf16(af, bf, acc[tc], 0, 0, 0);
      }
    }
    if (t < 64) {
      float v = 0.f;
#pragma unroll 8
      for (int kk = 0; kk < 64; ++kk) v = fmaf(b2f(wa[t * LDP + kk]), xs[kk], v);
      vacc += v;
    }
  }
  __syncthreads();
  {  // epilogue: + bv[c]*Ksum[m], bounce bf16 [c][m] into wa
    const float4 b4 = *reinterpret_cast<const float4*>(&bv[c0 + w * 16 + kg * 4]);
    const float bva[4] = {b4.x, b4.y, b4.z, b4.w};
#pragma unroll
    for (int tc = 0; tc < 4; ++tc) {
      const float ksm = Ksum[b * M + tc * 16 + l15];
#pragma unroll
      for (int r = 0; r < 4; ++r)
        wa[(w * 16 + kg * 4 + r) * LDP + tc * 16 + l15] = f2b(acc[tc][r] + bva[r] * ksm);
    }
  }
  __syncthreads();
  {
    short* gp = matMT + ((size_t)b * C + c0 + sr) * M + sko;
    *reinterpret_cast<short8v*>(gp) = *reinterpret_cast<const short8v*>(&wa[sr * LDP + sko]);
    *reinterpret_cast<short8v*>(gp + 8) = *reinterpret_cast<const short8v*>(&wa[sr * LDP + sko + 8]);
  }
  if (t < 64) vsum[b * C + c0 + t] = vacc + 4096.0f * bv[c0 + t];
}

// ---------------------------------------------------------------------------
// final: D[c][n] = matMT[c][mK] x QnT[n][mK]; out = x + g*tl[n]*(vsum[c]+D).
// cy-split x2 (1024 blocks); T14 prefetch of matMT tile and epilogue x tile.
// ---------------------------------------------------------------------------
__global__ __launch_bounds__(256) void final_kernel(
    const float* __restrict__ x, const short* __restrict__ QnT,
    const float* __restrict__ Ksum, const short* __restrict__ matMT,
    const float* __restrict__ vsum, const float* __restrict__ gamma,
    float* __restrict__ out) {
  __shared__ short qb[64 * LDP];   // B = QnT [n][m]
  __shared__ short ab[64 * LDP];   // A = matMT [c][m]
  __shared__ float bo[64 * LDPF];  // f32 bounce [c][n]
  __shared__ float ke[64];
  __shared__ float tl[64];
  __shared__ float red2[256];
  const int t = threadIdx.x;
  const int n0 = blockIdx.x * 64;
  const int cy = blockIdx.y;
  const int b = blockIdx.z;
  const int w = t >> 6, l = t & 63, l15 = l & 15, kg = l >> 4;
  const int sr = t >> 2, sko = (t & 3) * 16;
  {
    const short* qg = &QnT[((size_t)b * N + n0 + sr) * M + sko];
    *reinterpret_cast<short8v*>(&qb[sr * LDP + sko]) = *reinterpret_cast<const short8v*>(qg);
    *reinterpret_cast<short8v*>(&qb[sr * LDP + sko + 8]) = *reinterpret_cast<const short8v*>(qg + 8);
  }
  if (t < 64) ke[t] = Ksum[b * M + t] + EPS;
  __syncthreads();
  {
    const int n = t & 63, mq = t >> 6;
    float d = 0.f;
#pragma unroll
    for (int j = 0; j < 16; ++j) d = fmaf(b2f(qb[n * LDP + mq * 16 + j]), ke[mq * 16 + j], d);
    red2[t] = d;
  }
  __syncthreads();
  if (t < 64)
    tl[t] = 1.0f / (4096.0f + red2[t] + red2[64 + t] + red2[128 + t] + red2[192 + t]);
  const float g = gamma[0];
  short8v ar0, ar1;
  {  // prologue: matMT tile for cc=0
    const short* mp = &matMT[((size_t)b * C + cy * 256 + sr) * M + sko];
    ar0 = *reinterpret_cast<const short8v*>(mp);
    ar1 = *reinterpret_cast<const short8v*>(mp + 8);
  }
  for (int cc = 0; cc < 4; ++cc) {
    const int c0 = cy * 256 + cc * 64;
    __syncthreads();  // prev epilogue bo reads + prev MFMA ab reads done
    *reinterpret_cast<short8v*>(&ab[sr * LDP + sko]) = ar0;
    *reinterpret_cast<short8v*>(&ab[sr * LDP + sko + 8]) = ar1;
    __syncthreads();
    if (cc < 3) {  // T14: next matMT tile
      const short* mp = &matMT[((size_t)b * C + c0 + 64 + sr) * M + sko];
      ar0 = *reinterpret_cast<const short8v*>(mp);
      ar1 = *reinterpret_cast<const short8v*>(mp + 8);
    }
    float4 xr[4];  // this tile's x for the epilogue (hides under MFMA)
    {
      const float* xp = &x[((size_t)b * C + c0 + sr) * N + n0 + sko];
#pragma unroll
      for (int i = 0; i < 4; ++i) xr[i] = *reinterpret_cast<const float4*>(xp + 4 * i);
    }
    f32x4 acc[4];
#pragma unroll
    for (int i = 0; i < 4; ++i) acc[i] = f32x4{0.f, 0.f, 0.f, 0.f};
#pragma unroll
    for (int ks = 0; ks < 2; ++ks) {
      const short8v af = *reinterpret_cast<const short8v*>(&ab[(w * 16 + l15) * LDP + ks * 32 + kg * 8]);
#pragma unroll
      for (int tc = 0; tc < 4; ++tc) {
        const short8v bf = *reinterpret_cast<const short8v*>(&qb[(tc * 16 + l15) * LDP + ks * 32 + kg * 8]);
        acc[tc] = __builtin_amdgcn_mfma_f32_16x16x32_bf16(af, bf, acc[tc], 0, 0, 0);
      }
    }
#pragma unroll
    for (int tc = 0; tc < 4; ++tc)
#pragma unroll
      for (int r = 0; r < 4; ++r)
        bo[(w * 16 + kg * 4 + r) * LDPF + tc * 16 + l15] = acc[tc][r];
    __syncthreads();
    {
      const int c = c0 + sr;
      const float vs = vsum[b * C + c];
      const size_t off = ((size_t)b * C + c) * N + n0 + sko;
#pragma unroll
      for (int i = 0; i < 4; ++i) {
        const float4 dv = *reinterpret_cast<const float4*>(&bo[sr * LDPF + sko + 4 * i]);
        const float4 tv = *reinterpret_cast<const float4*>(&tl[sko + 4 * i]);
        float4 o;
        o.x = xr[i].x + g * tv.x * (vs + dv.x);
        o.y = xr[i].y + g * tv.y * (vs + dv.y);
        o.z = xr[i].z + g * tv.z * (vs + dv.z);
        o.w = xr[i].w + g * tv.w * (vs + dv.w);
        *reinterpret_cast<float4*>(&out[off + 4 * i]) = o;
      }
    }
  }
}

// ---------------------------------------------------------------------------
extern "C" void kernel_launch(void* const* d_in, const int* in_sizes, int n_in,
                              void* d_out, int out_size, void* d_ws, size_t ws_size,
                              hipStream_t stream) {
  (void)in_sizes; (void)n_in; (void)out_size; (void)ws_size;
  const float* x = (const float*)d_in[0];
  const float* Wq = (const float*)d_in[1];
  const float* bq = (const float*)d_in[2];
  const float* Wk = (const float*)d_in[3];
  const float* bk = (const float*)d_in[4];
  const float* Wv = (const float*)d_in[5];
  const float* bv = (const float*)d_in[6];
  const float* gamma = (const float*)d_in[7];
  float* out = (float*)d_out;

  // ws layout, ~18 MB total
  char* wp = (char*)d_ws;
  short* Wq_bf = (short*)wp;  wp += (size_t)C * M * 2;
  short* Wk_bf = (short*)wp;  wp += (size_t)C * M * 2;
  short* Wv_bf = (short*)wp;  wp += (size_t)C * C * 2;
  short* KnB   = (short*)wp;  wp += (size_t)B * M * N * 2;
  short* QnT   = (short*)wp;  wp += (size_t)B * N * M * 2;
  short* matMT = (short*)wp;  wp += (size_t)B * C * M * 2;
  short* Spart = (short*)wp;  wp += (size_t)NTS * B * M * C * 2;
  float* Ksum  = (float*)wp;  wp += (size_t)B * M * 4;
  float* xsum  = (float*)wp;  wp += (size_t)B * C * 4;
  float* vsum  = (float*)wp;  wp += (size_t)B * C * 4;

  prep_kernel<<<256, 256, 0, stream>>>(Wq, Wk, Wv, Wq_bf, Wk_bf, Wv_bf, Ksum, xsum);
  qk_kernel<<<dim3(N / 64, B), 256, 0, stream>>>(x, Wq_bf, bq, Wk_bf, bk, QnT, KnB, Ksum);
  s_kernel<<<dim3(C / 64, NTS, B), 256, 0, stream>>>(x, KnB, Spart, xsum);
  matm_kernel<<<dim3(C / 64, B), 256, 0, stream>>>(Wv_bf, bv, Spart, xsum, Ksum, matMT, vsum);
  final_kernel<<<dim3(N / 64, 2, B), 256, 0, stream>>>(x, QnT, Ksum, matMT, vsum, gamma, out);
}